// Round 1
// baseline (254.240 us; speedup 1.0000x reference)
//
#include <hip/hip_runtime.h>

// Hierarchical loss, collapsed form:
//   win_i = 0.5*rowsum + 0.25*sum(100-block of t) + 0.125*(sum(10-block of t) + outputs[i,t])
//   loss  = sum_i (1 - win_i)
// Pure streaming reduction over outputs [B=32768, C=1000] fp32 -> HBM-bound (~131 MB read).

constexpr int C_COLS = 1000;
constexpr int F4_PER_ROW = 250;   // 1000 / 4

__global__ __launch_bounds__(256) void hloss_kernel(
    const float* __restrict__ outputs,
    const int*   __restrict__ target,
    float* __restrict__ loss)
{
    const int wave = threadIdx.x >> 6;          // 4 waves / block
    const int lane = threadIdx.x & 63;
    const int row  = (blockIdx.x << 2) | wave;  // one row per wave

    const int t     = target[row];
    const int lo100 = (t / 100) * 100;
    const int lo10  = (t / 10)  * 10;

    const float4* rp = reinterpret_cast<const float4*>(outputs + (size_t)row * C_COLS);

    float tot = 0.f, s100 = 0.f, s10e = 0.f;    // s10e = 10-block sum + target element

#pragma unroll
    for (int k = 0; k < 4; ++k) {
        const int f = (k << 6) + lane;          // float4 index within row [0, 250)
        if (f < F4_PER_ROW) {
            const float4 v = rp[f];
            const int c = f << 2;
            const float e[4] = {v.x, v.y, v.z, v.w};
#pragma unroll
            for (int j = 0; j < 4; ++j) {
                const int   cc = c + j;
                const float ee = e[j];
                tot  += ee;
                s100 += (cc >= lo100 && cc < lo100 + 100) ? ee : 0.f;
                s10e += (cc >= lo10  && cc < lo10  + 10 ) ? ee : 0.f;
                s10e += (cc == t) ? ee : 0.f;
            }
        }
    }

    // 64-lane butterfly reduction
#pragma unroll
    for (int off = 32; off >= 1; off >>= 1) {
        tot  += __shfl_xor(tot,  off, 64);
        s100 += __shfl_xor(s100, off, 64);
        s10e += __shfl_xor(s10e, off, 64);
    }

    __shared__ float part[4];
    if (lane == 0) {
        const float win = 0.5f * tot + 0.25f * s100 + 0.125f * s10e;
        part[wave] = 1.0f - win;
    }
    __syncthreads();
    if (threadIdx.x == 0) {
        atomicAdd(loss, part[0] + part[1] + part[2] + part[3]);
    }
}

extern "C" void kernel_launch(void* const* d_in, const int* in_sizes, int n_in,
                              void* d_out, int out_size, void* d_ws, size_t ws_size,
                              hipStream_t stream)
{
    const float* outputs = (const float*)d_in[0];
    const int*   target  = (const int*)d_in[1];
    float*       loss    = (float*)d_out;

    const int B = in_sizes[1];                  // 32768 rows (targets)

    // d_out is re-poisoned to 0xAA before every timed launch -> zero it on-stream.
    hipMemsetAsync(loss, 0, sizeof(float), stream);
    hloss_kernel<<<B / 4, 256, 0, stream>>>(outputs, target, loss);
}

// Round 3
// 185.762 us; speedup vs baseline: 1.3686x; 1.3686x over previous
//
#include <hip/hip_runtime.h>

// Hierarchical loss, collapsed form:
//   win_i = 0.5*rowsum + 0.25*sum(100-block of t) + 0.125*(sum(10-block of t) + outputs[i,t])
//   loss  = sum_i (1 - win_i) = B - sum_i win_i
// Two-stage: stage 1 writes per-block win-partials to d_ws (NO same-address
// atomics -- 8192 serialized LLC RMWs were the round-1 bottleneck),
// stage 2 reduces 8192 partials and writes B - total.

constexpr int C_COLS = 1000;
constexpr int F4_PER_ROW = 250;   // 1000 / 4

__global__ __launch_bounds__(256) void hloss_stage1(
    const float* __restrict__ outputs,
    const int*   __restrict__ target,
    float* __restrict__ partials)
{
    const int wave = threadIdx.x >> 6;          // 4 waves / block
    const int lane = threadIdx.x & 63;
    const int row  = (blockIdx.x << 2) | wave;  // one row per wave

    const int t     = target[row];
    const int lo100 = (t / 100) * 100;
    const int lo10  = (t / 10)  * 10;

    const float4* rp = reinterpret_cast<const float4*>(outputs + (size_t)row * C_COLS);

    float tot = 0.f, s100 = 0.f, s10e = 0.f;    // s10e = 10-block sum + target element

#pragma unroll
    for (int k = 0; k < 4; ++k) {
        const int f = (k << 6) + lane;          // float4 index within row [0, 250)
        if (f < F4_PER_ROW) {
            const float4 v = rp[f];
            const int c = f << 2;
            const float e[4] = {v.x, v.y, v.z, v.w};
#pragma unroll
            for (int j = 0; j < 4; ++j) {
                const int   cc = c + j;
                const float ee = e[j];
                tot  += ee;
                s100 += (cc >= lo100 && cc < lo100 + 100) ? ee : 0.f;
                s10e += (cc >= lo10  && cc < lo10  + 10 ) ? ee : 0.f;
                s10e += (cc == t) ? ee : 0.f;
            }
        }
    }

    // 64-lane butterfly reduction
#pragma unroll
    for (int off = 32; off >= 1; off >>= 1) {
        tot  += __shfl_xor(tot,  off, 64);
        s100 += __shfl_xor(s100, off, 64);
        s10e += __shfl_xor(s10e, off, 64);
    }

    __shared__ float part[4];
    if (lane == 0) {
        part[wave] = 0.5f * tot + 0.25f * s100 + 0.125f * s10e;  // win for this row
    }
    __syncthreads();
    if (threadIdx.x == 0) {
        partials[blockIdx.x] = part[0] + part[1] + part[2] + part[3];
    }
}

// Reduce nparts floats (nparts divisible by 1024 here: 8192) -> out[0] = Bf - sum
__global__ __launch_bounds__(256) void hloss_stage2(
    const float* __restrict__ partials,
    float* __restrict__ out,
    int n_f4, float Bf)
{
    const int lane = threadIdx.x & 63;
    const int wave = threadIdx.x >> 6;
    const float4* p = reinterpret_cast<const float4*>(partials);

    float s = 0.f;
    for (int i = threadIdx.x; i < n_f4; i += 256) {
        const float4 v = p[i];
        s += (v.x + v.y) + (v.z + v.w);
    }
#pragma unroll
    for (int off = 32; off >= 1; off >>= 1) {
        s += __shfl_xor(s, off, 64);
    }
    __shared__ float part[4];
    if (lane == 0) part[wave] = s;
    __syncthreads();
    if (threadIdx.x == 0) {
        out[0] = Bf - (part[0] + part[1] + part[2] + part[3]);
    }
}

extern "C" void kernel_launch(void* const* d_in, const int* in_sizes, int n_in,
                              void* d_out, int out_size, void* d_ws, size_t ws_size,
                              hipStream_t stream)
{
    const float* outputs = (const float*)d_in[0];
    const int*   target  = (const int*)d_in[1];
    float*       loss    = (float*)d_out;
    float*       partials = (float*)d_ws;

    const int B = in_sizes[1];                  // 32768 rows
    const int nblocks = B / 4;                  // 8192 partials

    hloss_stage1<<<nblocks, 256, 0, stream>>>(outputs, target, partials);
    hloss_stage2<<<1, 256, 0, stream>>>(partials, loss, nblocks / 4, (float)B);
}